// Round 1
// baseline (39636.063 us; speedup 1.0000x reference)
//
#include <hip/hip_runtime.h>
#include <math.h>

#define B_TOT 2048
#define T_LEN 256
#define D_IN  131
#define NH1   64
#define NH2   32
#define NG1   256   // 4*H1
#define NG2   128   // 4*H2
#define BT    8     // batch rows per workgroup
#define NWG   (B_TOT / BT)   // 256
#define NTHR  512

#define KC1   33    // ceil(131/4) k-chunks for W_ih1
#define KH1   16    // 64/4
#define KI2   16    // 64/4
#define KH2   8     // 32/4

__device__ __forceinline__ float sigmoidf_(float x) {
    // safe: exp(-x) -> inf for very negative x gives 1/(1+inf)=0, no NaN
    return 1.0f / (1.0f + __expf(-x));
}
__device__ __forceinline__ float tanhf_(float x) {
    // overflow-safe tanh
    float ax = fabsf(x);
    float e  = __expf(-2.0f * ax);      // in (0,1], never overflows
    float t  = (1.0f - e) / (1.0f + e);
    return copysignf(t, x);
}

// Transpose W_ih1 [256][131] -> ws chunk layout [33][256][4] (zero-padded k)
__global__ void prep_wih1(const float* __restrict__ W_ih1, float* __restrict__ wih1c) {
    int i = blockIdx.x * 256 + threadIdx.x;
    if (i >= KC1 * NG1 * 4) return;
    int kc = i >> 10;              // /1024
    int g  = (i >> 2) & (NG1 - 1);
    int j  = i & 3;
    int k  = kc * 4 + j;
    wih1c[i] = (k < D_IN) ? W_ih1[g * D_IN + k] : 0.0f;
}

__global__ __launch_bounds__(NTHR, 2) void lstm_fused(
    const float* __restrict__ x,       // [B,T,131]
    const float* __restrict__ wih1c,   // ws [33][256][4]
    const float* __restrict__ W_hh1,   // [256][64]
    const float* __restrict__ b_ih1, const float* __restrict__ b_hh1,
    const float* __restrict__ W_ih2,   // [128][64]
    const float* __restrict__ W_hh2,   // [128][32]
    const float* __restrict__ b_ih2, const float* __restrict__ b_hh2,
    const float* __restrict__ W_fc,    // [4][32]
    const float* __restrict__ b_fc,
    float* __restrict__ out)           // [B,4]
{
    // weights in chunk-4 layout [kc][gate][4] -> every read is ds_read_b128,
    // wave-consecutive across lanes (conflict-free)
    __shared__ __attribute__((aligned(16))) float wh1[KH1 * NG1 * 4];  // 64KB
    __shared__ __attribute__((aligned(16))) float wi2[KI2 * NG2 * 4];  // 32KB
    __shared__ __attribute__((aligned(16))) float wh2[KH2 * NG2 * 4];  // 16KB
    __shared__ __attribute__((aligned(16))) float xt[BT][132];         // 4.2KB (pad col 131 = 0)
    __shared__ __attribute__((aligned(16))) float h1s[BT][NH1];        // 2KB
    __shared__ __attribute__((aligned(16))) float h2s[BT][NH2];        // 1KB
    __shared__ __attribute__((aligned(16))) float g1s[BT][NG1];        // 8KB (activated gates)
    __shared__ __attribute__((aligned(16))) float g2s[BT][NG2];        // 4KB

    const int tid = threadIdx.x;
    const int b0  = blockIdx.x * BT;

    // ---- one-time LDS fills (transpose to [kc][g][4]) ----
    for (int i = tid; i < KH1 * NG1 * 4; i += NTHR) {
        int kc = i >> 10, g = (i >> 2) & 255, j = i & 3;
        wh1[i] = W_hh1[g * NH1 + kc * 4 + j];
    }
    for (int i = tid; i < KI2 * NG2 * 4; i += NTHR) {
        int kc = i >> 9, n = (i >> 2) & 127, j = i & 3;
        wi2[i] = W_ih2[n * NH1 + kc * 4 + j];
    }
    for (int i = tid; i < KH2 * NG2 * 4; i += NTHR) {
        int kc = i >> 9, n = (i >> 2) & 127, j = i & 3;
        wh2[i] = W_hh2[n * NH2 + kc * 4 + j];
    }
    for (int i = tid; i < BT * NH1; i += NTHR) ((float*)h1s)[i] = 0.0f;
    if (tid < BT * NH2) ((float*)h2s)[tid] = 0.0f;
    if (tid < BT) xt[tid][131] = 0.0f;   // k-pad; weight pad is 0 too

    // ---- per-thread fixed assignments ----
    const int g1  = tid & (NG1 - 1);     // layer-1 gate index (two half-blocks of threads)
    const int bq  = (tid >> 8) * 4;      // batch quad: threads 0-255 -> b 0..3, 256-511 -> b 4..7
    const float bias1 = b_ih1[g1] + b_hh1[g1];
    const int n2  = tid & (NG2 - 1);     // layer-2 gate index
    const int bh  = tid >> 7;            // 0..3 ; handles batches bh and bh+4
    const float bias2 = b_ih2[n2] + b_hh2[n2];
    const int cb1 = tid >> 6, cj1 = tid & 63;   // layer-1 cell (b, j), 512 units
    float c1 = 0.0f;
    const int cb2 = tid >> 5, cj2 = tid & 31;   // layer-2 cell (b, j), 256 units (tid<256)
    float c2 = 0.0f;

    const bool isg1 = (g1 >= 128) && (g1 < 192);  // wave-uniform
    const bool isg2 = (n2 >= 64) && (n2 < 96);

    __syncthreads();

    const float*  xb  = x + (size_t)b0 * T_LEN * D_IN;
    const float4* wg  = (const float4*)wih1c;
    const float4* wr  = (const float4*)wh1;
    const float4* wiv = (const float4*)wi2;
    const float4* whv = (const float4*)wh2;

    for (int t = 0; t < T_LEN; ++t) {
        // ---- A) stage x[:, t, :] into LDS (coalesced 64-lane runs) ----
        {
            const int bb = tid >> 6;          // 0..7
            const int kk = tid & 63;
            const float* src = xb + (size_t)bb * T_LEN * D_IN + (size_t)t * D_IN;
            #pragma unroll
            for (int m = 0; m < 3; ++m) {
                int k = kk + 64 * m;
                if (k < D_IN) xt[bb][k] = src[k];
            }
        }
        __syncthreads();

        // ---- B) layer-1 gates: G1[b][g1] for 4 batches ----
        {
            float a0 = bias1, a1 = bias1, a2 = bias1, a3 = bias1;
            // input projection: stream pre-transposed W_ih1 from L2, dwordx4 coalesced
            for (int kc = 0; kc < KC1; ++kc) {
                float4 w  = wg[kc * NG1 + g1];
                float4 x0 = *(const float4*)&xt[bq + 0][kc * 4];
                float4 x1 = *(const float4*)&xt[bq + 1][kc * 4];
                float4 x2 = *(const float4*)&xt[bq + 2][kc * 4];
                float4 x3 = *(const float4*)&xt[bq + 3][kc * 4];
                a0 += x0.x * w.x + x0.y * w.y + x0.z * w.z + x0.w * w.w;
                a1 += x1.x * w.x + x1.y * w.y + x1.z * w.z + x1.w * w.w;
                a2 += x2.x * w.x + x2.y * w.y + x2.z * w.z + x2.w * w.w;
                a3 += x3.x * w.x + x3.y * w.y + x3.z * w.z + x3.w * w.w;
            }
            // recurrent part from LDS
            for (int kc = 0; kc < KH1; ++kc) {
                float4 w  = wr[kc * NG1 + g1];
                float4 h0 = *(const float4*)&h1s[bq + 0][kc * 4];
                float4 h1 = *(const float4*)&h1s[bq + 1][kc * 4];
                float4 h2 = *(const float4*)&h1s[bq + 2][kc * 4];
                float4 h3 = *(const float4*)&h1s[bq + 3][kc * 4];
                a0 += h0.x * w.x + h0.y * w.y + h0.z * w.z + h0.w * w.w;
                a1 += h1.x * w.x + h1.y * w.y + h1.z * w.z + h1.w * w.w;
                a2 += h2.x * w.x + h2.y * w.y + h2.z * w.z + h2.w * w.w;
                a3 += h3.x * w.x + h3.y * w.y + h3.z * w.z + h3.w * w.w;
            }
            g1s[bq + 0][g1] = isg1 ? tanhf_(a0) : sigmoidf_(a0);
            g1s[bq + 1][g1] = isg1 ? tanhf_(a1) : sigmoidf_(a1);
            g1s[bq + 2][g1] = isg1 ? tanhf_(a2) : sigmoidf_(a2);
            g1s[bq + 3][g1] = isg1 ? tanhf_(a3) : sigmoidf_(a3);
        }
        __syncthreads();

        // ---- C) layer-1 cell/hidden update (1 unit per thread) ----
        {
            float gi = g1s[cb1][cj1];
            float gf = g1s[cb1][cj1 + 64];
            float gg = g1s[cb1][cj1 + 128];
            float go = g1s[cb1][cj1 + 192];
            c1 = gf * c1 + gi * gg;
            h1s[cb1][cj1] = go * tanhf_(c1);
        }
        __syncthreads();

        // ---- D) layer-2 gates: G2[b][n2] for batches bh and bh+4 ----
        {
            float a0 = bias2, a1 = bias2;
            for (int kc = 0; kc < KI2; ++kc) {
                float4 w = wiv[kc * NG2 + n2];
                float4 p = *(const float4*)&h1s[bh][kc * 4];
                float4 q = *(const float4*)&h1s[bh + 4][kc * 4];
                a0 += p.x * w.x + p.y * w.y + p.z * w.z + p.w * w.w;
                a1 += q.x * w.x + q.y * w.y + q.z * w.z + q.w * w.w;
            }
            for (int kc = 0; kc < KH2; ++kc) {
                float4 w = whv[kc * NG2 + n2];
                float4 p = *(const float4*)&h2s[bh][kc * 4];
                float4 q = *(const float4*)&h2s[bh + 4][kc * 4];
                a0 += p.x * w.x + p.y * w.y + p.z * w.z + p.w * w.w;
                a1 += q.x * w.x + q.y * w.y + q.z * w.z + q.w * w.w;
            }
            g2s[bh][n2]     = isg2 ? tanhf_(a0) : sigmoidf_(a0);
            g2s[bh + 4][n2] = isg2 ? tanhf_(a1) : sigmoidf_(a1);
        }
        __syncthreads();

        // ---- E) layer-2 cell/hidden update ----
        if (tid < BT * NH2) {
            float gi = g2s[cb2][cj2];
            float gf = g2s[cb2][cj2 + 32];
            float gg = g2s[cb2][cj2 + 64];
            float go = g2s[cb2][cj2 + 96];
            c2 = gf * c2 + gi * gg;
            h2s[cb2][cj2] = go * tanhf_(c2);
        }
        __syncthreads();
    }

    // ---- F) FC head: out[b][cls] ----
    if (tid < BT * 4) {
        int b = tid >> 2, cls = tid & 3;
        float s = b_fc[cls];
        #pragma unroll
        for (int k = 0; k < NH2; ++k) s += h2s[b][k] * W_fc[cls * NH2 + k];
        out[(size_t)(b0 + b) * 4 + cls] = s;
    }
}

extern "C" void kernel_launch(void* const* d_in, const int* in_sizes, int n_in,
                              void* d_out, int out_size, void* d_ws, size_t ws_size,
                              hipStream_t stream) {
    const float* x     = (const float*)d_in[0];
    const float* W_ih1 = (const float*)d_in[1];
    const float* W_hh1 = (const float*)d_in[2];
    const float* b_ih1 = (const float*)d_in[3];
    const float* b_hh1 = (const float*)d_in[4];
    const float* W_ih2 = (const float*)d_in[5];
    const float* W_hh2 = (const float*)d_in[6];
    const float* b_ih2 = (const float*)d_in[7];
    const float* b_hh2 = (const float*)d_in[8];
    const float* W_fc  = (const float*)d_in[9];
    const float* b_fc  = (const float*)d_in[10];
    float* out   = (float*)d_out;
    float* wih1c = (float*)d_ws;   // needs 33*256*4*4 = 540,672 bytes

    prep_wih1<<<(KC1 * NG1 * 4 + 255) / 256, 256, 0, stream>>>(W_ih1, wih1c);
    lstm_fused<<<NWG, NTHR, 0, stream>>>(x, wih1c, W_hh1, b_ih1, b_hh1,
                                         W_ih2, W_hh2, b_ih2, b_hh2,
                                         W_fc, b_fc, out);
}

// Round 2
// 2323.254 us; speedup vs baseline: 17.0606x; 17.0606x over previous
//
#include <hip/hip_runtime.h>
#include <math.h>

#define B_TOT 2048
#define T_LEN 256
#define D_IN  131
#define NH1   64
#define NH2   32
#define NG1   256   // 4*H1
#define NG2   128   // 4*H2
#define BT    8     // batch rows per workgroup
#define NWG   (B_TOT / BT)   // 256
#define NTHR  512

#define KC1   33    // ceil(131/4) k-chunks for W_ih1
#define KC1P  35    // +2 zero chunks so depth-2 prefetch never branches
#define KH1   16    // 64/4
#define KI2   16    // 64/4
#define KH2   8     // 32/4

__device__ __forceinline__ float sigmoidf_(float x) {
    return 1.0f / (1.0f + __expf(-x));   // exp(-x)->inf for x<<0 gives 0, no NaN
}
__device__ __forceinline__ float tanhf_(float x) {
    float ax = fabsf(x);
    float e  = __expf(-2.0f * ax);       // in (0,1], never overflows
    float t  = (1.0f - e) / (1.0f + e);
    return copysignf(t, x);
}

// Transpose W_ih1 [256][131] -> ws chunk layout [35][256][4] (zero-padded k)
__global__ void prep_wih1(const float* __restrict__ W_ih1, float* __restrict__ wih1c) {
    int i = blockIdx.x * 256 + threadIdx.x;
    if (i >= KC1P * NG1 * 4) return;
    int kc = i >> 10;              // /1024
    int g  = (i >> 2) & (NG1 - 1);
    int j  = i & 3;
    int k  = kc * 4 + j;
    wih1c[i] = (k < D_IN) ? W_ih1[g * D_IN + k] : 0.0f;
}

__global__ __launch_bounds__(NTHR, 2) void lstm_fused(
    const float* __restrict__ x,       // [B,T,131]
    const float* __restrict__ wih1c,   // ws [35][256][4]
    const float* __restrict__ W_hh1,   // [256][64]
    const float* __restrict__ b_ih1, const float* __restrict__ b_hh1,
    const float* __restrict__ W_ih2,   // [128][64]
    const float* __restrict__ W_hh2,   // [128][32]
    const float* __restrict__ b_ih2, const float* __restrict__ b_hh2,
    const float* __restrict__ W_fc,    // [4][32]
    const float* __restrict__ b_fc,
    float* __restrict__ out)           // [B,4]
{
    __shared__ __attribute__((aligned(16))) float wh1[KH1 * NG1 * 4];   // 64KB [kc][g][4]
    __shared__ __attribute__((aligned(16))) float wi2[KI2 * NG2 * 4];   // 32KB [kc][n][4]
    __shared__ __attribute__((aligned(16))) float wh2[KH2 * NG2 * 4];   // 16KB [kc][n][4]
    __shared__ __attribute__((aligned(16))) float xt[BT][132];          // pad col 131 = 0
    __shared__ __attribute__((aligned(16))) float h1s[BT][NH1];
    __shared__ __attribute__((aligned(16))) float h2s[2][BT][NH2];      // ping-pong
    __shared__ __attribute__((aligned(16))) float g1s[BT][NG1];

    const int tid = threadIdx.x;
    const int b0  = blockIdx.x * BT;

    // ---- one-time LDS fills (transpose to [kc][g][4]) ----
    for (int i = tid; i < KH1 * NG1 * 4; i += NTHR) {
        int kc = i >> 10, g = (i >> 2) & 255, j = i & 3;
        wh1[i] = W_hh1[g * NH1 + kc * 4 + j];
    }
    for (int i = tid; i < KI2 * NG2 * 4; i += NTHR) {
        int kc = i >> 9, n = (i >> 2) & 127, j = i & 3;
        wi2[i] = W_ih2[n * NH1 + kc * 4 + j];
    }
    for (int i = tid; i < KH2 * NG2 * 4; i += NTHR) {
        int kc = i >> 9, n = (i >> 2) & 127, j = i & 3;
        wh2[i] = W_hh2[n * NH2 + kc * 4 + j];
    }
    for (int i = tid; i < BT * NH1; i += NTHR) ((float*)h1s)[i] = 0.0f;
    if (tid < BT * NH2) ((float*)h2s[0])[tid] = 0.0f;
    if (tid < BT) xt[tid][131] = 0.0f;

    // ---- per-thread fixed assignments ----
    const int g1  = tid & (NG1 - 1);     // layer-1 gate, two half-blocks
    const int bq  = (tid >> 8) * 4;      // batch quad base: 0 or 4
    const float bias1 = b_ih1[g1] + b_hh1[g1];
    const bool isg1 = (g1 >= 128) && (g1 < 192);   // wave-uniform (g-gate -> tanh)

    const int cb1 = tid >> 6, cj1 = tid & 63;      // layer-1 cell unit
    float c1 = 0.0f;

    const int db = (tid >> 5) & 7;       // layer-2: batch (tid<256)
    const int dj = tid & 31;             //          hidden unit j
    const float bi2_i = b_ih2[dj]      + b_hh2[dj];
    const float bi2_f = b_ih2[dj + 32] + b_hh2[dj + 32];
    const float bi2_g = b_ih2[dj + 64] + b_hh2[dj + 64];
    const float bi2_o = b_ih2[dj + 96] + b_hh2[dj + 96];
    float c2 = 0.0f;

    const float*  xb  = x + (size_t)b0 * T_LEN * D_IN;
    const float4* wgp = (const float4*)wih1c + g1;
    const float4* wr  = (const float4*)wh1;
    const float4* wiv = (const float4*)wi2;
    const float4* whv = (const float4*)wh2;

    // ---- stage x[:, 0, :] (all 512 threads, 64-lane runs) ----
    {
        const int bb = tid >> 6;
        const int kk = tid & 63;
        const float* src = xb + (size_t)bb * T_LEN * D_IN;
        #pragma unroll
        for (int m = 0; m < 3; ++m) {
            int k = kk + 64 * m;
            if (k < D_IN) xt[bb][k] = src[k];
        }
    }
    __syncthreads();

    for (int t = 0; t < T_LEN; ++t) {
        const int pp = t & 1;   // h2_prev buffer

        // ---- B) layer-1 gates: G1[bq..bq+3][g1] ----
        {
            float a0 = bias1, a1 = bias1, a2 = bias1, a3 = bias1;
            // in-proj: depth-2 register pipeline over global W stream
            float4 wA = wgp[0];
            float4 wB = wgp[NG1];
            #pragma unroll 2
            for (int kc = 0; kc < KC1; ++kc) {
                float4 wn = wgp[(kc + 2) * NG1];          // padded, never OOB
                float4 x0 = *(const float4*)&xt[bq + 0][kc * 4];
                float4 x1 = *(const float4*)&xt[bq + 1][kc * 4];
                float4 x2 = *(const float4*)&xt[bq + 2][kc * 4];
                float4 x3 = *(const float4*)&xt[bq + 3][kc * 4];
                a0 += x0.x * wA.x + x0.y * wA.y + x0.z * wA.z + x0.w * wA.w;
                a1 += x1.x * wA.x + x1.y * wA.y + x1.z * wA.z + x1.w * wA.w;
                a2 += x2.x * wA.x + x2.y * wA.y + x2.z * wA.z + x2.w * wA.w;
                a3 += x3.x * wA.x + x3.y * wA.y + x3.z * wA.z + x3.w * wA.w;
                wA = wB; wB = wn;
            }
            // recurrent part from LDS
            #pragma unroll 2
            for (int kc = 0; kc < KH1; ++kc) {
                float4 w  = wr[kc * NG1 + g1];
                float4 h0 = *(const float4*)&h1s[bq + 0][kc * 4];
                float4 h1 = *(const float4*)&h1s[bq + 1][kc * 4];
                float4 h2 = *(const float4*)&h1s[bq + 2][kc * 4];
                float4 h3 = *(const float4*)&h1s[bq + 3][kc * 4];
                a0 += h0.x * w.x + h0.y * w.y + h0.z * w.z + h0.w * w.w;
                a1 += h1.x * w.x + h1.y * w.y + h1.z * w.z + h1.w * w.w;
                a2 += h2.x * w.x + h2.y * w.y + h2.z * w.z + h2.w * w.w;
                a3 += h3.x * w.x + h3.y * w.y + h3.z * w.z + h3.w * w.w;
            }
            g1s[bq + 0][g1] = isg1 ? tanhf_(a0) : sigmoidf_(a0);
            g1s[bq + 1][g1] = isg1 ? tanhf_(a1) : sigmoidf_(a1);
            g1s[bq + 2][g1] = isg1 ? tanhf_(a2) : sigmoidf_(a2);
            g1s[bq + 3][g1] = isg1 ? tanhf_(a3) : sigmoidf_(a3);
        }
        __syncthreads();

        // ---- C) layer-1 cell/hidden update (1 unit per thread) ----
        {
            float gi = g1s[cb1][cj1];
            float gf = g1s[cb1][cj1 + 64];
            float gg = g1s[cb1][cj1 + 128];
            float go = g1s[cb1][cj1 + 192];
            c1 = gf * c1 + gi * gg;
            h1s[cb1][cj1] = go * tanhf_(c1);
        }
        __syncthreads();

        // ---- D+E) layer-2 full update by (b,j) thread | x(t+1) staging ----
        if (tid < 256) {
            float di = bi2_i, df = bi2_f, dg = bi2_g, dq = bi2_o;
            #pragma unroll 2
            for (int kc = 0; kc < KI2; ++kc) {
                float4 h  = *(const float4*)&h1s[db][kc * 4];
                float4 w0 = wiv[kc * NG2 + dj];
                float4 w1 = wiv[kc * NG2 + dj + 32];
                float4 w2 = wiv[kc * NG2 + dj + 64];
                float4 w3 = wiv[kc * NG2 + dj + 96];
                di += h.x * w0.x + h.y * w0.y + h.z * w0.z + h.w * w0.w;
                df += h.x * w1.x + h.y * w1.y + h.z * w1.z + h.w * w1.w;
                dg += h.x * w2.x + h.y * w2.y + h.z * w2.z + h.w * w2.w;
                dq += h.x * w3.x + h.y * w3.y + h.z * w3.z + h.w * w3.w;
            }
            #pragma unroll 2
            for (int kc = 0; kc < KH2; ++kc) {
                float4 h  = *(const float4*)&h2s[pp][db][kc * 4];
                float4 w0 = whv[kc * NG2 + dj];
                float4 w1 = whv[kc * NG2 + dj + 32];
                float4 w2 = whv[kc * NG2 + dj + 64];
                float4 w3 = whv[kc * NG2 + dj + 96];
                di += h.x * w0.x + h.y * w0.y + h.z * w0.z + h.w * w0.w;
                df += h.x * w1.x + h.y * w1.y + h.z * w1.z + h.w * w1.w;
                dg += h.x * w2.x + h.y * w2.y + h.z * w2.z + h.w * w2.w;
                dq += h.x * w3.x + h.y * w3.y + h.z * w3.z + h.w * w3.w;
            }
            float gi = sigmoidf_(di);
            float gf = sigmoidf_(df);
            float gg = tanhf_(dg);
            float go = sigmoidf_(dq);
            c2 = gf * c2 + gi * gg;
            h2s[pp ^ 1][db][dj] = go * tanhf_(c2);
        } else if (t + 1 < T_LEN) {
            const int bb = (tid >> 5) & 7;
            const int kk = tid & 31;
            const float* src = xb + (size_t)bb * T_LEN * D_IN + (size_t)(t + 1) * D_IN;
            #pragma unroll
            for (int m = 0; m < 5; ++m) {
                int k = kk + 32 * m;
                if (k < D_IN) xt[bb][k] = src[k];
            }
        }
        __syncthreads();
    }

    // ---- F) FC head ----
    if (tid < BT * 4) {
        int b = tid >> 2, cls = tid & 3;
        float s = b_fc[cls];
        #pragma unroll
        for (int k = 0; k < NH2; ++k) s += h2s[0][b][k] * W_fc[cls * NH2 + k];
        out[(size_t)(b0 + b) * 4 + cls] = s;
    }
}

extern "C" void kernel_launch(void* const* d_in, const int* in_sizes, int n_in,
                              void* d_out, int out_size, void* d_ws, size_t ws_size,
                              hipStream_t stream) {
    const float* x     = (const float*)d_in[0];
    const float* W_ih1 = (const float*)d_in[1];
    const float* W_hh1 = (const float*)d_in[2];
    const float* b_ih1 = (const float*)d_in[3];
    const float* b_hh1 = (const float*)d_in[4];
    const float* W_ih2 = (const float*)d_in[5];
    const float* W_hh2 = (const float*)d_in[6];
    const float* b_ih2 = (const float*)d_in[7];
    const float* b_hh2 = (const float*)d_in[8];
    const float* W_fc  = (const float*)d_in[9];
    const float* b_fc  = (const float*)d_in[10];
    float* out   = (float*)d_out;
    float* wih1c = (float*)d_ws;   // needs 35*256*4*4 = 573,440 bytes

    prep_wih1<<<(KC1P * NG1 * 4 + 255) / 256, 256, 0, stream>>>(W_ih1, wih1c);
    lstm_fused<<<NWG, NTHR, 0, stream>>>(x, wih1c, W_hh1, b_ih1, b_hh1,
                                         W_ih2, W_hh2, b_ih2, b_hh2,
                                         W_fc, b_fc, out);
}

// Round 3
// 739.530 us; speedup vs baseline: 53.5963x; 3.1415x over previous
//
#include <hip/hip_runtime.h>
#include <math.h>

#define B_TOT 2048
#define T_LEN 256
#define D_IN  131
#define NTHR  512

typedef __attribute__((ext_vector_type(8))) short s16x8;
typedef __attribute__((ext_vector_type(4))) float f32x4;

#define MFMA_B16(a,b,c) __builtin_amdgcn_mfma_f32_16x16x32_bf16(a, b, c, 0, 0, 0)

__device__ __forceinline__ float sigmoidf_(float x){ return 1.0f/(1.0f+__expf(-x)); }
__device__ __forceinline__ float tanhf_(float x){
    float ax=fabsf(x), e=__expf(-2.0f*ax), t=(1.0f-e)/(1.0f+e); return copysignf(t,x);
}
__device__ __forceinline__ unsigned short bfrne(float f){
    unsigned u = __float_as_uint(f);
    return (unsigned short)((u + 0x7fffu + ((u>>16)&1u)) >> 16);
}
__device__ __forceinline__ float bf2f(unsigned short h){
    return __uint_as_float(((unsigned)h)<<16);
}

// ws layout (shorts):
//   wbfT  [2][256][160]  @ 0        (hi/lo of W_ih1^T padded K131->160, k-minor)
//   whh1T [2][256][64]   @ 81920
//   w2T   [2][128][96]   @ 114688   (k 0..63 = W_ih2, k 64..95 = W_hh2)
#define WS_WIH1 0
#define WS_WHH1 81920
#define WS_W2   114688

__global__ void prep_w(const float* __restrict__ W_ih1, const float* __restrict__ W_hh1,
                       const float* __restrict__ W_ih2, const float* __restrict__ W_hh2,
                       short* __restrict__ wsS) {
    int i = blockIdx.x*256 + threadIdx.x;
    float v; int dst_hi, s_stride;
    if (i < 256*160) {
        int n = i/160, k = i - n*160;
        v = (k < D_IN) ? W_ih1[n*D_IN + k] : 0.0f;
        dst_hi = WS_WIH1 + n*160 + k; s_stride = 256*160;
    } else if (i < 256*160 + 256*64) {
        int j = i - 256*160; int n = j/64, k = j - n*64;
        v = W_hh1[n*64 + k];
        dst_hi = WS_WHH1 + n*64 + k; s_stride = 256*64;
    } else if (i < 256*160 + 256*64 + 128*96) {
        int j = i - (256*160 + 256*64); int n = j/96, k = j - n*96;
        v = (k < 64) ? W_ih2[n*64 + k] : W_hh2[n*32 + (k - 64)];
        dst_hi = WS_W2 + n*96 + k; s_stride = 128*96;
    } else return;
    unsigned short hi = bfrne(v);
    unsigned short lo = bfrne(v - bf2f(hi));
    wsS[dst_hi]            = (short)hi;
    wsS[dst_hi + s_stride] = (short)lo;
}

// One STEP: parity P (0/1), ACC = f32x4 (&)[2] window-acc tile for this step pair
#define STEP(P, ACC) do { \
  const int rowsel = (r & 7) + ((((r >> 3) ^ (P)) & 1) << 3); \
  _Pragma("unroll") \
  for (int kt = 0; kt < 2; ++kt) { \
    s16x8 ah = *(const s16x8*)&h1bf[(0*16 + rowsel)*72 + kt*32 + g4*8]; \
    s16x8 al = *(const s16x8*)&h1bf[(1*16 + rowsel)*72 + kt*32 + g4*8]; \
    _Pragma("unroll") \
    for (int nt = 0; nt < 2; ++nt) { \
      ACC[nt] = MFMA_B16(ah, whf[nt][kt][0], ACC[nt]); \
      ACC[nt] = MFMA_B16(ah, whf[nt][kt][1], ACC[nt]); \
      ACC[nt] = MFMA_B16(al, whf[nt][kt][0], ACC[nt]); \
    } \
  } \
  if (((g4 >> 1) & 1) == (P)) { \
    int bb = (g4 & 1)*4; \
    _Pragma("unroll") \
    for (int r2 = 0; r2 < 4; ++r2) { \
      _Pragma("unroll") \
      for (int nt = 0; nt < 2; ++nt) { \
        float v = ACC[nt][r2] + b1v[nt]; \
        g1s[(bb + r2)*256 + w*32 + nt*16 + r] = tanh1 ? tanhf_(v) : sigmoidf_(v); \
      } \
    } \
  } \
  __syncthreads(); \
  { float gi = g1s[cb*256 + cj], gf = g1s[cb*256 + 64 + cj]; \
    float gg = g1s[cb*256 + 128 + cj], go = g1s[cb*256 + 192 + cj]; \
    c1 = gf*c1 + gi*gg; \
    float h1v = go * tanhf_(c1); \
    unsigned short hh = bfrne(h1v); \
    h1bf[(0*16 + cb)*72 + cj] = (short)hh; \
    h1bf[(1*16 + cb)*72 + cj] = (short)bfrne(h1v - bf2f(hh)); } \
  __syncthreads(); \
  { f32x4 a2 = zero4; \
    _Pragma("unroll") \
    for (int kt = 0; kt < 2; ++kt) { \
      s16x8 ah = *(const s16x8*)&h1bf[(0*16 + rowsel)*72 + kt*32 + g4*8]; \
      s16x8 al = *(const s16x8*)&h1bf[(1*16 + rowsel)*72 + kt*32 + g4*8]; \
      a2 = MFMA_B16(ah, w2f[kt][0], a2); \
      a2 = MFMA_B16(ah, w2f[kt][1], a2); \
      a2 = MFMA_B16(al, w2f[kt][0], a2); \
    } \
    { s16x8 ah = *(const s16x8*)&h2bf[(0*16 + rowsel)*40 + g4*8]; \
      s16x8 al = *(const s16x8*)&h2bf[(1*16 + rowsel)*40 + g4*8]; \
      a2 = MFMA_B16(ah, w2f[2][0], a2); \
      a2 = MFMA_B16(ah, w2f[2][1], a2); \
      a2 = MFMA_B16(al, w2f[2][0], a2); } \
    if (((g4 >> 1) & 1) == (P)) { \
      int bb = (g4 & 1)*4; \
      _Pragma("unroll") \
      for (int r2 = 0; r2 < 4; ++r2) { \
        float v = a2[r2] + b2v; \
        g2s[(bb + r2)*128 + w*16 + r] = tanh2 ? tanhf_(v) : sigmoidf_(v); \
      } \
    } } \
  __syncthreads(); \
  if (tid < 256) { \
    float gi = g2s[eb*128 + ej], gf = g2s[eb*128 + 32 + ej]; \
    float gg = g2s[eb*128 + 64 + ej], go = g2s[eb*128 + 96 + ej]; \
    c2 = gf*c2 + gi*gg; \
    float h2v = go * tanhf_(c2); \
    unsigned short hh = bfrne(h2v); \
    h2bf[(0*16 + eb)*40 + ej] = (short)hh; \
    h2bf[(1*16 + eb)*40 + ej] = (short)bfrne(h2v - bf2f(hh)); \
    lastH2 = h2v; \
  } \
} while(0)

__global__ __launch_bounds__(NTHR, 2) void lstm_mfma(
    const float* __restrict__ x,
    const short* __restrict__ wsS,
    const float* __restrict__ b_ih1, const float* __restrict__ b_hh1,
    const float* __restrict__ b_ih2, const float* __restrict__ b_hh2,
    const float* __restrict__ W_fc,  const float* __restrict__ b_fc,
    float* __restrict__ out)
{
    // xbf: x-window bf16 hi/lo, rows m = trel*8 + b (M=64), cols k padded 168 (bank stagger)
    __shared__ __attribute__((aligned(16))) short xbf[2*64*168];
    // h1bf/h2bf: rows 0..7 real (b), rows 8..15 permanent zeros (M-pad); col pad for banks
    __shared__ __attribute__((aligned(16))) short h1bf[2*16*72];
    __shared__ __attribute__((aligned(16))) short h2bf[2*16*40];
    __shared__ __attribute__((aligned(16))) float g1s[8*256];
    __shared__ __attribute__((aligned(16))) float g2s[8*128];

    const int tid  = threadIdx.x;
    const int b0   = blockIdx.x * 8;
    const int w    = tid >> 6;      // wave 0..7
    const int lane = tid & 63;
    const int r    = lane & 15;     // row (A) / col (B,C/D) within 16-tile
    const int g4   = lane >> 4;     // k-group / C-row-group

    // zero LDS (xbf pads MUST be zero: k 131..159 read by MFMA; NaN*0=NaN hazard)
    for (int i = tid; i < (2*64*168)/2; i += NTHR) ((int*)xbf)[i] = 0;
    for (int i = tid; i < (2*16*72)/2;  i += NTHR) ((int*)h1bf)[i] = 0;
    for (int i = tid; i < (2*16*40)/2;  i += NTHR) ((int*)h2bf)[i] = 0;

    const short* wbfT  = wsS + WS_WIH1;
    const short* whh1T = wsS + WS_WHH1;
    const short* w2T   = wsS + WS_W2;

    // stationary recurrent weight fragments (B-operand: col = r, k = kt*32 + g4*8 + j)
    s16x8 whf[2][2][2];   // [nt][kt][s]
    #pragma unroll
    for (int nt = 0; nt < 2; ++nt)
    #pragma unroll
    for (int kt = 0; kt < 2; ++kt)
    #pragma unroll
    for (int s = 0; s < 2; ++s) {
        int n = w*32 + nt*16 + r;
        int k = kt*32 + g4*8;
        whf[nt][kt][s] = *(const s16x8*)(whh1T + (s*256 + n)*64 + k);
    }
    s16x8 w2f[3][2];      // [kt][s], K=96: k<64 from W_ih2, k>=64 from W_hh2
    #pragma unroll
    for (int kt = 0; kt < 3; ++kt)
    #pragma unroll
    for (int s = 0; s < 2; ++s) {
        int n = w*16 + r;
        int k = kt*32 + g4*8;
        w2f[kt][s] = *(const s16x8*)(w2T + (s*128 + n)*96 + k);
    }
    float b1v[2];
    #pragma unroll
    for (int nt = 0; nt < 2; ++nt) { int n = w*32 + nt*16 + r; b1v[nt] = b_ih1[n] + b_hh1[n]; }
    float b2v; { int n = w*16 + r; b2v = b_ih2[n] + b_hh2[n]; }

    const bool tanh1 = (w >= 4 && w < 6);   // L1 g-gate cols 128..191
    const bool tanh2 = (w >= 4 && w < 6);   // L2 g-gate cols 64..95

    const int cb = tid >> 6, cj = tid & 63;        // layer-1 cell (b==w? no: cb = tid>>6 = w; cj unit)
    float c1 = 0.0f;
    const int eb = (tid >> 5) & 7, ej = tid & 31;  // layer-2 cell (tid<256)
    float c2 = 0.0f;
    float lastH2 = 0.0f;
    const f32x4 zero4 = {0.f, 0.f, 0.f, 0.f};

    for (int w0 = 0; w0 < 32; ++w0) {
        const int t0 = w0 * 8;
        // ---- stage x window -> xbf (bf16 hi/lo), coalesced scalar loads ----
        for (int i = tid; i < 8*1048; i += NTHR) {
            int run  = i / 1048;            // batch within WG
            int rem  = i - run*1048;
            int trel = rem / 131;
            int k    = rem - trel*131;
            float v  = x[((size_t)(b0 + run)*T_LEN + t0 + trel)*D_IN + k];
            int m    = trel*8 + run;
            unsigned short hi = bfrne(v);
            xbf[(0*64 + m)*168 + k] = (short)hi;
            xbf[(1*64 + m)*168 + k] = (short)bfrne(v - bf2f(hi));
        }
        __syncthreads();

        // ---- in-proj window GEMM: M=64, N=256 (wave n-slice 32), K=160 ----
        f32x4 accw[4][2];
        #pragma unroll
        for (int u = 0; u < 4; ++u)
        #pragma unroll
        for (int nt = 0; nt < 2; ++nt) accw[u][nt] = zero4;

        #pragma unroll
        for (int kt = 0; kt < 5; ++kt) {
            s16x8 bfr[2][2];
            #pragma unroll
            for (int nt = 0; nt < 2; ++nt)
            #pragma unroll
            for (int s = 0; s < 2; ++s)
                bfr[nt][s] = *(const s16x8*)(wbfT + (s*256 + w*32 + nt*16 + r)*160 + kt*32 + g4*8);
            #pragma unroll
            for (int u = 0; u < 4; ++u) {
                s16x8 ah = *(const s16x8*)&xbf[(0*64 + u*16 + r)*168 + kt*32 + g4*8];
                s16x8 al = *(const s16x8*)&xbf[(1*64 + u*16 + r)*168 + kt*32 + g4*8];
                #pragma unroll
                for (int nt = 0; nt < 2; ++nt) {
                    accw[u][nt] = MFMA_B16(ah, bfr[nt][0], accw[u][nt]);
                    accw[u][nt] = MFMA_B16(ah, bfr[nt][1], accw[u][nt]);
                    accw[u][nt] = MFMA_B16(al, bfr[nt][0], accw[u][nt]);
                }
            }
        }

        // ---- 8 recurrent steps (2 per acc tile; parity selects row half) ----
        #pragma unroll
        for (int u = 0; u < 4; ++u) {
            STEP(0, accw[u]);
            STEP(1, accw[u]);
        }
    }

    __syncthreads();
    if (tid < 256) g1s[eb*32 + ej] = lastH2;   // stash final h2 (f32) in g1s row space
    __syncthreads();
    if (tid < 32) {
        int b = tid >> 2, cls = tid & 3;
        float s = b_fc[cls];
        #pragma unroll
        for (int k2 = 0; k2 < 32; ++k2) s += g1s[b*32 + k2] * W_fc[cls*32 + k2];
        out[(size_t)(b0 + b)*4 + cls] = s;
    }
}

extern "C" void kernel_launch(void* const* d_in, const int* in_sizes, int n_in,
                              void* d_out, int out_size, void* d_ws, size_t ws_size,
                              hipStream_t stream) {
    const float* x     = (const float*)d_in[0];
    const float* W_ih1 = (const float*)d_in[1];
    const float* W_hh1 = (const float*)d_in[2];
    const float* b_ih1 = (const float*)d_in[3];
    const float* b_hh1 = (const float*)d_in[4];
    const float* W_ih2 = (const float*)d_in[5];
    const float* W_hh2 = (const float*)d_in[6];
    const float* b_ih2 = (const float*)d_in[7];
    const float* b_hh2 = (const float*)d_in[8];
    const float* W_fc  = (const float*)d_in[9];
    const float* b_fc  = (const float*)d_in[10];
    float* out = (float*)d_out;
    short* wsS = (short*)d_ws;   // needs 278,528 bytes

    const int prep_elems = 256*160 + 256*64 + 128*96;
    prep_w<<<(prep_elems + 255)/256, 256, 0, stream>>>(W_ih1, W_hh1, W_ih2, W_hh2, wsS);
    lstm_mfma<<<B_TOT/8, NTHR, 0, stream>>>(x, wsS, b_ih1, b_hh1, b_ih2, b_hh2,
                                            W_fc, b_fc, out);
}

// Round 5
// 572.857 us; speedup vs baseline: 69.1901x; 1.2910x over previous
//
#include <hip/hip_runtime.h>
#include <math.h>

#define B_TOT 2048
#define T_LEN 256
#define D_IN  131
#define NTHR  512

typedef __attribute__((ext_vector_type(8))) short s16x8;
typedef __attribute__((ext_vector_type(4))) float f32x4;

#define MFMA_B16(a,b,c) __builtin_amdgcn_mfma_f32_16x16x32_bf16(a, b, c, 0, 0, 0)

// LDS geometry (shorts)
#define PLX  (2*32*168)   // one x buffer: [plane][32][168]
#define PLH1 (2*16*72)    // one h1 buffer: [plane][16][72]
#define PLH2 (2*16*40)    // one h2 buffer: [plane][16][40]

// ws layout (shorts): wih1 hi/lo [2][256][160] @0 ; whh1 hi/lo [2][256][64] @81920 ;
// w2 hi/lo [2][128][96] @114688  (k<64 = W_ih2, k>=64 = W_hh2)
#define WS_WIH1_LO 40960
#define WS_WHH1    81920
#define WS_W2      114688
#define PREP_N     (40960 + 16384 + 12288)

__device__ __forceinline__ float rcp_(float x){ return __builtin_amdgcn_rcpf(x); }
__device__ __forceinline__ float sigmoidf_(float x){ return rcp_(1.0f + __expf(-x)); }
__device__ __forceinline__ float tanhf_(float x){
    float ax = fabsf(x);
    float e  = __expf(-2.0f * ax);
    float t  = (1.0f - e) * rcp_(1.0f + e);
    return copysignf(t, x);
}
__device__ __forceinline__ unsigned short bfrne(float f){
    unsigned u = __float_as_uint(f);
    return (unsigned short)((u + 0x7fffu + ((u>>16)&1u)) >> 16);
}
__device__ __forceinline__ float bf2f(unsigned short h){
    return __uint_as_float(((unsigned)h)<<16);
}

// Column permutation: tile col packs [i-units(8) | f-units(8)] / [g | o] per wave.
__global__ void prep_w(const float* __restrict__ W_ih1, const float* __restrict__ W_hh1,
                       const float* __restrict__ W_ih2, const float* __restrict__ W_hh2,
                       short* __restrict__ wsS) {
    int i = blockIdx.x*256 + threadIdx.x;
    if (i >= PREP_N) return;
    if (i < 40960) {                       // W_ih1 hi/lo: [n'][160]
        int np = i / 160, k = i - np*160;
        int u = (np>>5)*8 + (np&7);
        int gate = ((np>>4)&1)*2 + ((np>>3)&1);
        int n = gate*64 + u;
        float v = (k < D_IN) ? W_ih1[n*D_IN + k] : 0.0f;
        unsigned short hi = bfrne(v);
        wsS[i]              = (short)hi;
        wsS[WS_WIH1_LO + i] = (short)bfrne(v - bf2f(hi));
    } else if (i < 40960 + 16384) {        // W_hh1 hi/lo: [n'][64]
        int j = i - 40960;
        int np = j >> 6, k = j & 63;
        int u = (np>>5)*8 + (np&7);
        int gate = ((np>>4)&1)*2 + ((np>>3)&1);
        int n = gate*64 + u;
        float v = W_hh1[n*64 + k];
        unsigned short hi = bfrne(v);
        wsS[WS_WHH1 + j]         = (short)hi;
        wsS[WS_WHH1 + 16384 + j] = (short)bfrne(v - bf2f(hi));
    } else {                               // W_ih2|W_hh2 hi/lo: [n'][96]
        int j = i - (40960 + 16384);
        int np = j / 96, k = j - np*96;
        int u = ((np>>5)&3)*8 + (np&7);
        int gate = ((np>>4)&1)*2 + ((np>>3)&1);
        int n = gate*32 + u;
        float v = (k < 64) ? W_ih2[n*64 + k] : W_hh2[n*32 + (k - 64)];
        unsigned short hi = bfrne(v);
        wsS[WS_W2 + j]         = (short)hi;
        wsS[WS_W2 + 12288 + j] = (short)bfrne(v - bf2f(hi));
    }
}

// ---- PHASE1: layer-1 gates + in-register cell update. U,P compile-time. ----
// Exchange rule: keep regs {q} (loR, rows 4g4+0..1) / {2+q} (hiR, rows 4g4+2..3);
// SEND the opposite half so both pair-threads see i,f (and g,o) of the SAME rows.
#define PHASE1(U, P) do { \
  const short* h1r = h1bf + (P)*PLH1; \
  short*       h1w = h1bf + (1-(P))*PLH1; \
  const int rsel = (r & 7) + ((((r >> 3) ^ (P)) & 1) << 3); \
  s16x8 ah0 = *(const s16x8*)&h1r[rsel*72 + g4*8]; \
  s16x8 ah1 = *(const s16x8*)&h1r[rsel*72 + 32 + g4*8]; \
  s16x8 al0 = *(const s16x8*)&h1r[(16+rsel)*72 + g4*8]; \
  s16x8 al1 = *(const s16x8*)&h1r[(16+rsel)*72 + 32 + g4*8]; \
  f32x4 rec0 = zero4, rec1 = zero4; \
  rec0 = MFMA_B16(ah0, whf[0][0][0], rec0);  rec1 = MFMA_B16(ah0, whf[1][0][0], rec1); \
  rec0 = MFMA_B16(ah1, whf[0][1][0], rec0);  rec1 = MFMA_B16(ah1, whf[1][1][0], rec1); \
  rec0 = MFMA_B16(ah0, whf[0][0][1], rec0);  rec1 = MFMA_B16(ah0, whf[1][0][1], rec1); \
  rec0 = MFMA_B16(ah1, whf[0][1][1], rec0);  rec1 = MFMA_B16(ah1, whf[1][1][1], rec1); \
  rec0 = MFMA_B16(al0, whf[0][0][0], rec0);  rec1 = MFMA_B16(al0, whf[1][0][0], rec1); \
  rec0 = MFMA_B16(al1, whf[0][1][0], rec0);  rec1 = MFMA_B16(al1, whf[1][1][0], rec1); \
  const bool act1 = ((g4 >> 1) == (P)); \
  _Pragma("unroll") \
  for (int q = 0; q < 2; ++q) { \
    float kA = (hiR ? accw[U][0][2+q] + rec0[2+q] : accw[U][0][q]   + rec0[q]); \
    float sA = (hiR ? accw[U][0][q]   + rec0[q]   : accw[U][0][2+q] + rec0[2+q]); \
    float kB = (hiR ? accw[U][1][2+q] + rec1[2+q] : accw[U][1][q]   + rec1[q]); \
    float sB = (hiR ? accw[U][1][q]   + rec1[q]   : accw[U][1][2+q] + rec1[2+q]); \
    float pA = __shfl_xor(sA, 8); \
    float pB = __shfl_xor(sB, 8); \
    float gi = sigmoidf_((hiR ? pA : kA) + bi1); \
    float gf = sigmoidf_((hiR ? kA : pA) + bf1); \
    float gg = tanhf_   ((hiR ? pB : kB) + bg1); \
    float go = sigmoidf_((hiR ? kB : pB) + bo1); \
    float cn = gf * c1[q] + gi * gg; \
    float cx = __shfl_xor(cn, 32); \
    c1[q] = act1 ? cn : cx; \
    if (act1) { \
      float hv = go * tanhf_(cn); \
      int row = ((g4 & 1) << 2) + ((r >> 3) << 1) + q; \
      unsigned short hh = bfrne(hv); \
      h1w[row*72 + u1c]      = (short)hh; \
      h1w[(16+row)*72 + u1c] = (short)bfrne(hv - bf2f(hh)); \
    } \
  } \
} while(0)

// ---- PHASE2: layer-2 gates + cell (waves 0-3). P compile-time. ----
#define PHASE2(P) do { \
  const short* h1n = h1bf + (1-(P))*PLH1; \
  const short* h2r = h2bf + (P)*PLH2; \
  short*       h2w = h2bf + (1-(P))*PLH2; \
  s16x8 ah0 = *(const s16x8*)&h1n[r*72 + g4*8]; \
  s16x8 ah1 = *(const s16x8*)&h1n[r*72 + 32 + g4*8]; \
  s16x8 al0 = *(const s16x8*)&h1n[(16+r)*72 + g4*8]; \
  s16x8 al1 = *(const s16x8*)&h1n[(16+r)*72 + 32 + g4*8]; \
  s16x8 bh  = *(const s16x8*)&h2r[r*40 + g4*8]; \
  s16x8 bl  = *(const s16x8*)&h2r[(16+r)*40 + g4*8]; \
  f32x4 p0 = zero4, p1 = zero4, q0 = zero4, q1 = zero4; \
  p0 = MFMA_B16(ah0, w2f[0][0][0], p0);  p1 = MFMA_B16(ah0, w2f[1][0][0], p1); \
  p0 = MFMA_B16(ah1, w2f[0][1][0], p0);  p1 = MFMA_B16(ah1, w2f[1][1][0], p1); \
  p0 = MFMA_B16(bh,  w2f[0][2][0], p0);  p1 = MFMA_B16(bh,  w2f[1][2][0], p1); \
  q0 = MFMA_B16(ah0, w2f[0][0][1], q0);  q1 = MFMA_B16(ah0, w2f[1][0][1], q1); \
  q0 = MFMA_B16(ah1, w2f[0][1][1], q0);  q1 = MFMA_B16(ah1, w2f[1][1][1], q1); \
  q0 = MFMA_B16(bh,  w2f[0][2][1], q0);  q1 = MFMA_B16(bh,  w2f[1][2][1], q1); \
  q0 = MFMA_B16(al0, w2f[0][0][0], q0);  q1 = MFMA_B16(al0, w2f[1][0][0], q1); \
  q0 = MFMA_B16(al1, w2f[0][1][0], q0);  q1 = MFMA_B16(al1, w2f[1][1][0], q1); \
  q0 = MFMA_B16(bl,  w2f[0][2][0], q0);  q1 = MFMA_B16(bl,  w2f[1][2][0], q1); \
  const bool act2 = (g4 < 2); \
  _Pragma("unroll") \
  for (int qq = 0; qq < 2; ++qq) { \
    float kA = (hiR ? p0[2+qq] + q0[2+qq] : p0[qq]   + q0[qq]); \
    float sA = (hiR ? p0[qq]   + q0[qq]   : p0[2+qq] + q0[2+qq]); \
    float kB = (hiR ? p1[2+qq] + q1[2+qq] : p1[qq]   + q1[qq]); \
    float sB = (hiR ? p1[qq]   + q1[qq]   : p1[2+qq] + q1[2+qq]); \
    float pA = __shfl_xor(sA, 8); \
    float pB = __shfl_xor(sB, 8); \
    float gi = sigmoidf_((hiR ? pA : kA) + l2bi); \
    float gf = sigmoidf_((hiR ? kA : pA) + l2bf); \
    float gg = tanhf_   ((hiR ? pB : kB) + l2bg); \
    float go = sigmoidf_((hiR ? kB : pB) + l2bo); \
    float cn = gf * c2[qq] + gi * gg; \
    c2[qq] = cn; \
    if (act2) { \
      float hv = go * tanhf_(cn); \
      h2last[qq] = hv; \
      int row = (g4 << 2) + ((r >> 3) << 1) + qq; \
      unsigned short hh = bfrne(hv); \
      h2w[row*40 + u2c]      = (short)hh; \
      h2w[(16+row)*40 + u2c] = (short)bfrne(hv - bf2f(hh)); \
    } \
  } \
} while(0)

// ---- STAGE: waves 4-7 write chunk S of next window, prefetch next chunk. ----
#define STAGE(S) do { \
  if (w0 < 63) { \
    _Pragma("unroll") \
    for (int m = 0; m < 5; ++m) { \
      if (m < 4 || sv4) { \
        int mrow = (S)*8 + runm[m]; \
        unsigned short hh = bfrne(xr[m]); \
        xn[mrow*168 + km[m]]      = (short)hh; \
        xn[(32+mrow)*168 + km[m]] = (short)bfrne(xr[m] - bf2f(hh)); \
      } \
    } \
    if ((S) < 3 || w0 <= 61) { \
      int tl = ((S) < 3) ? ((w0+1)*4 + (S) + 1) : ((w0+2)*4); \
      _Pragma("unroll") \
      for (int m = 0; m < 5; ++m) \
        if (m < 4 || sv4) xr[m] = x[(size_t)(offm[m] + tl*131)]; \
    } \
  } \
} while(0)

__global__ __launch_bounds__(NTHR, 2) void lstm_mfma(
    const float* __restrict__ x,
    const short* __restrict__ wsS,
    const float* __restrict__ b_ih1, const float* __restrict__ b_hh1,
    const float* __restrict__ b_ih2, const float* __restrict__ b_hh2,
    const float* __restrict__ W_fc,  const float* __restrict__ b_fc,
    float* __restrict__ out)
{
    __shared__ __attribute__((aligned(16))) short xbf[2*PLX];    // 43008 B
    __shared__ __attribute__((aligned(16))) short h1bf[2*PLH1];  //  9216 B
    __shared__ __attribute__((aligned(16))) short h2bf[2*PLH2];  //  5120 B
    __shared__ __attribute__((aligned(16))) float h2f[256];      //  1024 B

    const int tid  = threadIdx.x;
    const int b0   = blockIdx.x * 8;
    const int w    = tid >> 6;
    const int lane = tid & 63;
    const int r    = lane & 15;
    const int g4   = lane >> 4;
    const bool hiR = (r >= 8);
    const int u1c  = w*8 + (r & 7);
    const int u2c  = (w & 3)*8 + (r & 7);
    const f32x4 zero4 = {0.f, 0.f, 0.f, 0.f};

    // zero LDS (pads must be 0: MFMA reads k up to 159; h rows 8-15 are the M-pad)
    for (int i = tid; i < 2*PLX/2;  i += NTHR) ((int*)xbf)[i]  = 0;
    for (int i = tid; i < 2*PLH1/2; i += NTHR) ((int*)h1bf)[i] = 0;
    for (int i = tid; i < 2*PLH2/2; i += NTHR) ((int*)h2bf)[i] = 0;

    // stationary weight fragments (registers)
    s16x8 wbf[5][2];      // in-proj W hi   [kt][nt]
    s16x8 wlo[5][2];      // in-proj W lo   [kt][nt]
    s16x8 whf[2][2][2];   // W_hh1 hi/lo    [nt][kt][s]
    s16x8 w2f[2][3][2];   // L2 W hi/lo     [nt][kt][s]  (kt2 = h2 block)
    #pragma unroll
    for (int kt = 0; kt < 5; ++kt)
      #pragma unroll
      for (int nt = 0; nt < 2; ++nt) {
        wbf[kt][nt] = *(const s16x8*)(wsS + (w*32 + nt*16 + r)*160 + kt*32 + g4*8);
        wlo[kt][nt] = *(const s16x8*)(wsS + WS_WIH1_LO + (w*32 + nt*16 + r)*160 + kt*32 + g4*8);
      }
    #pragma unroll
    for (int nt = 0; nt < 2; ++nt)
      #pragma unroll
      for (int kt = 0; kt < 2; ++kt)
        #pragma unroll
        for (int sp = 0; sp < 2; ++sp)
          whf[nt][kt][sp] = *(const s16x8*)(wsS + WS_WHH1 + sp*16384 +
                                            (w*32 + nt*16 + r)*64 + kt*32 + g4*8);
    #pragma unroll
    for (int nt = 0; nt < 2; ++nt)
      #pragma unroll
      for (int kt = 0; kt < 3; ++kt)
        #pragma unroll
        for (int sp = 0; sp < 2; ++sp)
          w2f[nt][kt][sp] = *(const s16x8*)(wsS + WS_W2 + sp*12288 +
                                            ((w&3)*32 + nt*16 + r)*96 + kt*32 + g4*8);

    const float bi1 = b_ih1[u1c]       + b_hh1[u1c];
    const float bf1 = b_ih1[64 + u1c]  + b_hh1[64 + u1c];
    const float bg1 = b_ih1[128 + u1c] + b_hh1[128 + u1c];
    const float bo1 = b_ih1[192 + u1c] + b_hh1[192 + u1c];
    const float l2bi = b_ih2[u2c]      + b_hh2[u2c];
    const float l2bf = b_ih2[32 + u2c] + b_hh2[32 + u2c];
    const float l2bg = b_ih2[64 + u2c] + b_hh2[64 + u2c];
    const float l2bo = b_ih2[96 + u2c] + b_hh2[96 + u2c];

    float c1[2] = {0.f, 0.f}, c2[2] = {0.f, 0.f}, h2last[2] = {0.f, 0.f};

    // stager lane constants (waves 4-7 use them)
    const int t2 = tid & 255;
    int runm[5], km[5], offm[5];
    const bool sv4 = (t2 < 24);
    #pragma unroll
    for (int m = 0; m < 5; ++m) {
        int j = t2 + 256*m;
        int rn = j / 131;
        runm[m] = rn; km[m] = j - rn*131;
        offm[m] = (b0 + rn)*33536 + km[m];     // + t*131 at load time
    }
    float xr[5] = {0.f,0.f,0.f,0.f,0.f};

    __syncthreads();   // zeros visible before data writes

    // prologue: stage window 0 into buf 0 (all threads)
    for (int i = tid; i < 4192; i += NTHR) {
        int rn = i / 524; int rem = i - rn*524;
        int tr = rem / 131; int k = rem - tr*131;
        float v = x[(size_t)(b0 + rn)*33536 + tr*131 + k];
        int mrow = tr*8 + rn;
        unsigned short hh = bfrne(v);
        xbf[mrow*168 + k]      = (short)hh;
        xbf[(32+mrow)*168 + k] = (short)bfrne(v - bf2f(hh));
    }
    if (w >= 4) {   // prefetch chunk 0 of window 1
        #pragma unroll
        for (int m = 0; m < 5; ++m)
            if (m < 4 || sv4) xr[m] = x[(size_t)(offm[m] + 4*131)];
    }
    __syncthreads();

    f32x4 accw[2][2];

    for (int w0 = 0; w0 < 64; ++w0) {
        const int cur = w0 & 1;
        const short* xc = xbf + cur*PLX;
        short* xn = xbf + (cur^1)*PLX;

        // ---- in-proj window GEMM: M=32 (4 steps x 8 batch), N=256, K=160 ----
        // 3-term hi/lo: xh*Wh + xl*Wh + xh*Wl  (xl*Wl ~2^-18, dropped)
        #pragma unroll
        for (int u = 0; u < 2; ++u)
          #pragma unroll
          for (int nt = 0; nt < 2; ++nt) accw[u][nt] = zero4;
        #pragma unroll
        for (int kt = 0; kt < 5; ++kt) {
          #pragma unroll
          for (int u = 0; u < 2; ++u) {
            s16x8 xh = *(const s16x8*)&xc[(u*16 + r)*168 + kt*32 + g4*8];
            s16x8 xl = *(const s16x8*)&xc[(32 + u*16 + r)*168 + kt*32 + g4*8];
            accw[u][0] = MFMA_B16(xh, wbf[kt][0], accw[u][0]);
            accw[u][1] = MFMA_B16(xh, wbf[kt][1], accw[u][1]);
            accw[u][0] = MFMA_B16(xl, wbf[kt][0], accw[u][0]);
            accw[u][1] = MFMA_B16(xl, wbf[kt][1], accw[u][1]);
            accw[u][0] = MFMA_B16(xh, wlo[kt][0], accw[u][0]);
            accw[u][1] = MFMA_B16(xh, wlo[kt][1], accw[u][1]);
          }
        }

        // ---- 4 steps, 1 barrier each + 1 end-of-window ----
        PHASE1(0, 0);
        __syncthreads();
        if (w < 4) { PHASE2(0); } else { STAGE(0); }

        PHASE1(0, 1);
        __syncthreads();
        if (w < 4) { PHASE2(1); } else { STAGE(1); }

        PHASE1(1, 0);
        __syncthreads();
        if (w < 4) { PHASE2(0); } else { STAGE(2); }

        PHASE1(1, 1);
        __syncthreads();
        if (w < 4) { PHASE2(1); } else { STAGE(3); }

        __syncthreads();   // xbf[next] complete; h-buffers settled
    }

    // ---- FC head ----
    if (w < 4 && g4 < 2) {
        #pragma unroll
        for (int q = 0; q < 2; ++q)
            h2f[((g4 << 2) + ((r >> 3) << 1) + q)*32 + u2c] = h2last[q];
    }
    __syncthreads();
    if (tid < 32) {
        int b = tid >> 2, cls = tid & 3;
        float s = b_fc[cls];
        #pragma unroll
        for (int k2 = 0; k2 < 32; ++k2) s += h2f[b*32 + k2] * W_fc[cls*32 + k2];
        out[(size_t)(b0 + b)*4 + cls] = s;
    }
}

extern "C" void kernel_launch(void* const* d_in, const int* in_sizes, int n_in,
                              void* d_out, int out_size, void* d_ws, size_t ws_size,
                              hipStream_t stream) {
    const float* x     = (const float*)d_in[0];
    const float* W_ih1 = (const float*)d_in[1];
    const float* W_hh1 = (const float*)d_in[2];
    const float* b_ih1 = (const float*)d_in[3];
    const float* b_hh1 = (const float*)d_in[4];
    const float* W_ih2 = (const float*)d_in[5];
    const float* W_hh2 = (const float*)d_in[6];
    const float* b_ih2 = (const float*)d_in[7];
    const float* b_hh2 = (const float*)d_in[8];
    const float* W_fc  = (const float*)d_in[9];
    const float* b_fc  = (const float*)d_in[10];
    float* out = (float*)d_out;
    short* wsS = (short*)d_ws;   // needs 278,528 bytes

    prep_w<<<(PREP_N + 255)/256, 256, 0, stream>>>(W_ih1, W_hh1, W_ih2, W_hh2, wsS);
    lstm_mfma<<<B_TOT/8, NTHR, 0, stream>>>(x, wsS, b_ih1, b_hh1, b_ih2, b_hh2,
                                            W_fc, b_fc, out);
}

// Round 6
// 316.197 us; speedup vs baseline: 125.3526x; 1.8117x over previous
//
#include <hip/hip_runtime.h>
#include <math.h>

#define B_TOT 2048
#define T_LEN 256
#define D_IN  131
#define NTHR  512

typedef __attribute__((ext_vector_type(8))) short s16x8;
typedef __attribute__((ext_vector_type(4))) float f32x4;

#define MFMA_B16(a,b,c) __builtin_amdgcn_mfma_f32_16x16x32_bf16(a, b, c, 0, 0, 0)

// LDS geometry (shorts)
#define PLX   (2*32*168)   // one x buffer: [plane(hi/lo)][32 rows][168]
#define PLH1  (24*72)      // h1 buffer: rows 0-7 hi, 8-15 lo, 16-23 zero
#define PLH2  (24*40)      // h2 buffer: same row scheme

// ws layout (shorts): wih1 hi/lo [2][256][160] @0 (k=131 row = folded bias);
// whh1 hi/lo @81920 ; w2 hi/lo @114688 (k<64 = W_ih2, k>=64 = W_hh2)
#define WS_WIH1_LO 40960
#define WS_WHH1    81920
#define WS_W2      114688
#define PREP_N     (40960 + 16384 + 12288)

__device__ __forceinline__ float rcp_(float x){ return __builtin_amdgcn_rcpf(x); }
__device__ __forceinline__ float sigmoidf_(float x){ return rcp_(1.0f + __expf(-x)); }
__device__ __forceinline__ float tanhf_(float x){
    float ax = fabsf(x);
    float e  = __expf(-2.0f * ax);
    float t  = (1.0f - e) * rcp_(1.0f + e);
    return copysignf(t, x);
}
__device__ __forceinline__ unsigned short bfrne(float f){
    unsigned u = __float_as_uint(f);
    return (unsigned short)((u + 0x7fffu + ((u>>16)&1u)) >> 16);
}
__device__ __forceinline__ float bf2f(unsigned short h){
    return __uint_as_float(((unsigned)h)<<16);
}

// Column permutation: tile col packs [i-units(8) | f-units(8)] / [g | o] per wave.
__global__ void prep_w(const float* __restrict__ W_ih1, const float* __restrict__ W_hh1,
                       const float* __restrict__ W_ih2, const float* __restrict__ W_hh2,
                       const float* __restrict__ b_ih1, const float* __restrict__ b_hh1,
                       short* __restrict__ wsS) {
    int i = blockIdx.x*256 + threadIdx.x;
    if (i >= PREP_N) return;
    if (i < 40960) {                       // W_ih1 hi/lo: [n'][160], k=131 -> bias
        int np = i / 160, k = i - np*160;
        int u = (np>>5)*8 + (np&7);
        int gate = ((np>>4)&1)*2 + ((np>>3)&1);
        int n = gate*64 + u;
        float v;
        if (k < D_IN)       v = W_ih1[n*D_IN + k];
        else if (k == D_IN) v = b_ih1[n] + b_hh1[n];
        else                v = 0.0f;
        unsigned short hi = bfrne(v);
        wsS[i]              = (short)hi;
        wsS[WS_WIH1_LO + i] = (short)bfrne(v - bf2f(hi));
    } else if (i < 40960 + 16384) {        // W_hh1 hi/lo: [n'][64]
        int j = i - 40960;
        int np = j >> 6, k = j & 63;
        int u = (np>>5)*8 + (np&7);
        int gate = ((np>>4)&1)*2 + ((np>>3)&1);
        int n = gate*64 + u;
        float v = W_hh1[n*64 + k];
        unsigned short hi = bfrne(v);
        wsS[WS_WHH1 + j]         = (short)hi;
        wsS[WS_WHH1 + 16384 + j] = (short)bfrne(v - bf2f(hi));
    } else {                               // W_ih2|W_hh2 hi/lo: [n'][96]
        int j = i - (40960 + 16384);
        int np = j / 96, k = j - np*96;
        int u = ((np>>5)&3)*8 + (np&7);
        int gate = ((np>>4)&1)*2 + ((np>>3)&1);
        int n = gate*32 + u;
        float v = (k < 64) ? W_ih2[n*64 + k] : W_hh2[n*32 + (k - 64)];
        unsigned short hi = bfrne(v);
        wsS[WS_W2 + j]         = (short)hi;
        wsS[WS_W2 + 12288 + j] = (short)bfrne(v - bf2f(hi));
    }
}

// ---- PHASE1: layer-1. Rec MFMAs accumulate into accw[U] (zero A-rows keep the
// other parity's rows intact). Pre-acts scatter to per-wave gpre region, every
// lane gathers its own cell (b=lane>>3, u=lane&7) -- same-wave, no barrier. ----
#define PHASE1(U, P) do { \
  const short* h1r = h1bf + (P)*PLH1; \
  short*       h1w = h1bf + (1-(P))*PLH1; \
  const int rH = (r & 7) + 16*(((r >> 3) ^ (P)) & 1); \
  const int rL = 8 + (r & 7) + 8*(((r >> 3) ^ (P)) & 1); \
  s16x8 ah0 = *(const s16x8*)&h1r[rH*72 + g4*8]; \
  s16x8 ah1 = *(const s16x8*)&h1r[rH*72 + 32 + g4*8]; \
  s16x8 al0 = *(const s16x8*)&h1r[rL*72 + g4*8]; \
  s16x8 al1 = *(const s16x8*)&h1r[rL*72 + 32 + g4*8]; \
  accw[U][0] = MFMA_B16(ah0, whf[0][0][0], accw[U][0]); \
  accw[U][1] = MFMA_B16(ah0, whf[1][0][0], accw[U][1]); \
  accw[U][0] = MFMA_B16(ah1, whf[0][1][0], accw[U][0]); \
  accw[U][1] = MFMA_B16(ah1, whf[1][1][0], accw[U][1]); \
  accw[U][0] = MFMA_B16(ah0, whf[0][0][1], accw[U][0]); \
  accw[U][1] = MFMA_B16(ah0, whf[1][0][1], accw[U][1]); \
  accw[U][0] = MFMA_B16(ah1, whf[0][1][1], accw[U][0]); \
  accw[U][1] = MFMA_B16(ah1, whf[1][1][1], accw[U][1]); \
  accw[U][0] = MFMA_B16(al0, whf[0][0][0], accw[U][0]); \
  accw[U][1] = MFMA_B16(al0, whf[1][0][0], accw[U][1]); \
  accw[U][0] = MFMA_B16(al1, whf[0][1][0], accw[U][0]); \
  accw[U][1] = MFMA_B16(al1, whf[1][1][0], accw[U][1]); \
  if ((g4 >> 1) == (P)) { \
    *(f32x4*)(gw0 + 4*(g4 & 1)) = accw[U][0]; \
    *(f32x4*)(gw1 + 4*(g4 & 1)) = accw[U][1]; \
  } \
  float gi = sigmoidf_(gp[0]);     /* bias folded via k=131 column */ \
  float gf = sigmoidf_(gp[64]); \
  float gg = tanhf_   (gp[128]); \
  float go = sigmoidf_(gp[192]); \
  c1 = gf * c1 + gi * gg; \
  float hv = go * tanhf_(c1); \
  unsigned short hh = bfrne(hv); \
  h1w[bq*72 + u1g]     = (short)hh; \
  h1w[(8+bq)*72 + u1g] = (short)bfrne(hv - bf2f(hh)); \
} while(0)

// ---- PHASE2: layer-2 (waves 0-3), same scatter/gather scheme. ----
#define PHASE2(P) do { \
  const short* h1n = h1bf + (1-(P))*PLH1; \
  const short* h2r = h2bf + (P)*PLH2; \
  short*       h2w = h2bf + (1-(P))*PLH2; \
  const int rH2 = (r & 7) + 16*(r >> 3); \
  const int rL2 = 8 + (r & 7) + 8*(r >> 3); \
  s16x8 ah0 = *(const s16x8*)&h1n[rH2*72 + g4*8]; \
  s16x8 ah1 = *(const s16x8*)&h1n[rH2*72 + 32 + g4*8]; \
  s16x8 al0 = *(const s16x8*)&h1n[rL2*72 + g4*8]; \
  s16x8 al1 = *(const s16x8*)&h1n[rL2*72 + 32 + g4*8]; \
  s16x8 bh  = *(const s16x8*)&h2r[rH2*40 + g4*8]; \
  s16x8 bl  = *(const s16x8*)&h2r[rL2*40 + g4*8]; \
  f32x4 p0 = zero4, p1 = zero4; \
  p0 = MFMA_B16(ah0, w2f[0][0][0], p0);  p1 = MFMA_B16(ah0, w2f[1][0][0], p1); \
  p0 = MFMA_B16(ah1, w2f[0][1][0], p0);  p1 = MFMA_B16(ah1, w2f[1][1][0], p1); \
  p0 = MFMA_B16(bh,  w2f[0][2][0], p0);  p1 = MFMA_B16(bh,  w2f[1][2][0], p1); \
  p0 = MFMA_B16(ah0, w2f[0][0][1], p0);  p1 = MFMA_B16(ah0, w2f[1][0][1], p1); \
  p0 = MFMA_B16(ah1, w2f[0][1][1], p0);  p1 = MFMA_B16(ah1, w2f[1][1][1], p1); \
  p0 = MFMA_B16(bh,  w2f[0][2][1], p0);  p1 = MFMA_B16(bh,  w2f[1][2][1], p1); \
  p0 = MFMA_B16(al0, w2f[0][0][0], p0);  p1 = MFMA_B16(al0, w2f[1][0][0], p1); \
  p0 = MFMA_B16(al1, w2f[0][1][0], p0);  p1 = MFMA_B16(al1, w2f[1][1][0], p1); \
  p0 = MFMA_B16(bl,  w2f[0][2][0], p0);  p1 = MFMA_B16(bl,  w2f[1][2][0], p1); \
  if (g4 < 2) { \
    *(f32x4*)(gw0 + 4*g4) = p0; \
    *(f32x4*)(gw1 + 4*g4) = p1; \
  } \
  float gi = sigmoidf_(gp[0]   + l2bi); \
  float gf = sigmoidf_(gp[64]  + l2bf); \
  float gg = tanhf_   (gp[128] + l2bg); \
  float go = sigmoidf_(gp[192] + l2bo); \
  c2 = gf * c2 + gi * gg; \
  float hv = go * tanhf_(c2); \
  h2last = hv; \
  unsigned short hh = bfrne(hv); \
  h2w[bq*40 + u2i]     = (short)hh; \
  h2w[(8+bq)*40 + u2i] = (short)bfrne(hv - bf2f(hh)); \
} while(0)

// ---- STAGE: waves 4-7 write chunk S of next window, prefetch next chunk. ----
#define STAGE(S) do { \
  if (w0 < 63) { \
    _Pragma("unroll") \
    for (int m = 0; m < 5; ++m) { \
      if (m < 4 || sv4) { \
        int mrow = (S)*8 + runm[m]; \
        unsigned short hh = bfrne(xr[m]); \
        xn[mrow*168 + km[m]]      = (short)hh; \
        xn[(32+mrow)*168 + km[m]] = (short)bfrne(xr[m] - bf2f(hh)); \
      } \
    } \
    if ((S) < 3 || w0 <= 61) { \
      int tl = ((S) < 3) ? ((w0+1)*4 + (S) + 1) : ((w0+2)*4); \
      _Pragma("unroll") \
      for (int m = 0; m < 5; ++m) \
        if (m < 4 || sv4) xr[m] = x[(size_t)(offm[m] + tl*131)]; \
    } \
  } \
} while(0)

__global__ __launch_bounds__(NTHR, 1) void lstm_mfma(
    const float* __restrict__ x,
    const short* __restrict__ wsS,
    const float* __restrict__ b_ih2, const float* __restrict__ b_hh2,
    const float* __restrict__ W_fc,  const float* __restrict__ b_fc,
    float* __restrict__ out)
{
    __shared__ __attribute__((aligned(16))) short xbf[2*PLX];    // 43008 B
    __shared__ __attribute__((aligned(16))) short h1bf[2*PLH1];  //  6912 B
    __shared__ __attribute__((aligned(16))) short h2bf[2*PLH2];  //  3840 B
    __shared__ __attribute__((aligned(16))) float gpre[2048];    //  8192 B (also FC stash)

    const int tid  = threadIdx.x;
    const int b0   = blockIdx.x * 8;
    const int w    = tid >> 6;
    const int lane = tid & 63;
    const int r    = lane & 15;
    const int g4   = lane >> 4;
    const int up   = lane & 7;     // owned unit within wave
    const int bq   = lane >> 3;    // owned batch 0..7
    const int u1g  = w*8 + up;     // owned L1 unit (col in h1 buffer)
    const int u2i  = (w & 3)*8 + up;  // owned L2 unit (waves 0-3)
    const f32x4 zero4 = {0.f, 0.f, 0.f, 0.f};

    // per-wave pre-act region: rows (w*2+nt)*16 + col, 8 slots (pad 8 -> <=2-way reads)
    float* gw0 = gpre + ((w*2 + 0)*16 + r)*8;
    float* gw1 = gpre + ((w*2 + 1)*16 + r)*8;
    const float* gp = gpre + (w*32 + up)*8 + bq;   // i/f/g/o at +0,+64,+128,+192

    // zero LDS (zero rows 16-23 of h-buffers are the MFMA M-pad; xbf pads feed MFMA)
    for (int i = tid; i < 2*PLX/2;  i += NTHR) ((int*)xbf)[i]  = 0;
    for (int i = tid; i < 2*PLH1/2; i += NTHR) ((int*)h1bf)[i] = 0;
    for (int i = tid; i < 2*PLH2/2; i += NTHR) ((int*)h2bf)[i] = 0;
    // constant bias column k=131 = 1.0 (hi plane; lo stays 0), both buffers
    if (tid < 64) {
        int bf_ = tid >> 5, m = tid & 31;
        xbf[bf_*PLX + m*168 + 131] = (short)0x3f80;
    }

    // stationary weight fragments (registers; launch_bounds(512,1) -> 256 VGPR cap)
    s16x8 wbf[5][2];      // in-proj W hi   [kt][nt]
    s16x8 wlo[5][2];      // in-proj W lo   [kt][nt]
    s16x8 whf[2][2][2];   // W_hh1 hi/lo    [nt][kt][s]
    s16x8 w2f[2][3][2];   // L2 W hi/lo     [nt][kt][s]  (kt2 = h2 block)
    #pragma unroll
    for (int kt = 0; kt < 5; ++kt)
      #pragma unroll
      for (int nt = 0; nt < 2; ++nt) {
        wbf[kt][nt] = *(const s16x8*)(wsS + (w*32 + nt*16 + r)*160 + kt*32 + g4*8);
        wlo[kt][nt] = *(const s16x8*)(wsS + WS_WIH1_LO + (w*32 + nt*16 + r)*160 + kt*32 + g4*8);
      }
    #pragma unroll
    for (int nt = 0; nt < 2; ++nt)
      #pragma unroll
      for (int kt = 0; kt < 2; ++kt)
        #pragma unroll
        for (int sp = 0; sp < 2; ++sp)
          whf[nt][kt][sp] = *(const s16x8*)(wsS + WS_WHH1 + sp*16384 +
                                            (w*32 + nt*16 + r)*64 + kt*32 + g4*8);
    #pragma unroll
    for (int nt = 0; nt < 2; ++nt)
      #pragma unroll
      for (int kt = 0; kt < 3; ++kt)
        #pragma unroll
        for (int sp = 0; sp < 2; ++sp)
          w2f[nt][kt][sp] = *(const s16x8*)(wsS + WS_W2 + sp*12288 +
                                            ((w&3)*32 + nt*16 + r)*96 + kt*32 + g4*8);

    const float l2bi = b_ih2[u2i]      + b_hh2[u2i];
    const float l2bf = b_ih2[32 + u2i] + b_hh2[32 + u2i];
    const float l2bg = b_ih2[64 + u2i] + b_hh2[64 + u2i];
    const float l2bo = b_ih2[96 + u2i] + b_hh2[96 + u2i];

    float c1 = 0.0f, c2 = 0.0f, h2last = 0.0f;

    // stager lane constants (waves 4-7)
    const int t2 = tid & 255;
    int runm[5], km[5], offm[5];
    const bool sv4 = (t2 < 24);
    #pragma unroll
    for (int m = 0; m < 5; ++m) {
        int j = t2 + 256*m;
        int rn = j / 131;
        runm[m] = rn; km[m] = j - rn*131;
        offm[m] = (b0 + rn)*33536 + km[m];
    }
    float xr[5] = {0.f,0.f,0.f,0.f,0.f};

    __syncthreads();   // zeros + bias column visible

    // prologue: stage window 0 into buf 0 (all threads)
    for (int i = tid; i < 4192; i += NTHR) {
        int rn = i / 524; int rem = i - rn*524;
        int tr = rem / 131; int k = rem - tr*131;
        float v = x[(size_t)(b0 + rn)*33536 + tr*131 + k];
        int mrow = tr*8 + rn;
        unsigned short hh = bfrne(v);
        xbf[mrow*168 + k]      = (short)hh;
        xbf[(32+mrow)*168 + k] = (short)bfrne(v - bf2f(hh));
    }
    if (w >= 4) {
        #pragma unroll
        for (int m = 0; m < 5; ++m)
            if (m < 4 || sv4) xr[m] = x[(size_t)(offm[m] + 4*131)];
    }
    __syncthreads();

    f32x4 accw[2][2];

    for (int w0 = 0; w0 < 64; ++w0) {
        const int cur = w0 & 1;
        const short* xc = xbf + cur*PLX;
        short* xn = xbf + (cur^1)*PLX;

        // ---- in-proj window GEMM: M=32 (4 steps x 8 batch), N=256, K=160(+bias) ----
        // 3-term hi/lo: xh*Wh + xl*Wh + xh*Wl
        #pragma unroll
        for (int u = 0; u < 2; ++u)
          #pragma unroll
          for (int nt = 0; nt < 2; ++nt) accw[u][nt] = zero4;
        #pragma unroll
        for (int kt = 0; kt < 5; ++kt) {
          #pragma unroll
          for (int u = 0; u < 2; ++u) {
            s16x8 xh = *(const s16x8*)&xc[(u*16 + r)*168 + kt*32 + g4*8];
            s16x8 xl = *(const s16x8*)&xc[(32 + u*16 + r)*168 + kt*32 + g4*8];
            accw[u][0] = MFMA_B16(xh, wbf[kt][0], accw[u][0]);
            accw[u][1] = MFMA_B16(xh, wbf[kt][1], accw[u][1]);
            accw[u][0] = MFMA_B16(xl, wbf[kt][0], accw[u][0]);
            accw[u][1] = MFMA_B16(xl, wbf[kt][1], accw[u][1]);
            accw[u][0] = MFMA_B16(xh, wlo[kt][0], accw[u][0]);
            accw[u][1] = MFMA_B16(xh, wlo[kt][1], accw[u][1]);
          }
        }

        // ---- 4 steps, 1 barrier each + 1 end-of-window ----
        PHASE1(0, 0);
        __syncthreads();
        if (w < 4) { PHASE2(0); } else { STAGE(0); }

        PHASE1(0, 1);
        __syncthreads();
        if (w < 4) { PHASE2(1); } else { STAGE(1); }

        PHASE1(1, 0);
        __syncthreads();
        if (w < 4) { PHASE2(0); } else { STAGE(2); }

        PHASE1(1, 1);
        __syncthreads();
        if (w < 4) { PHASE2(1); } else { STAGE(3); }

        __syncthreads();   // xbf[next] complete; h-buffers settled
    }

    // ---- FC head (reuse gpre as f32 stash of final h2) ----
    if (w < 4) gpre[bq*32 + u2i] = h2last;
    __syncthreads();
    if (tid < 32) {
        int b = tid >> 2, cls = tid & 3;
        float s = b_fc[cls];
        #pragma unroll
        for (int k2 = 0; k2 < 32; ++k2) s += gpre[b*32 + k2] * W_fc[cls*32 + k2];
        out[(size_t)(b0 + b)*4 + cls] = s;
    }
}

extern "C" void kernel_launch(void* const* d_in, const int* in_sizes, int n_in,
                              void* d_out, int out_size, void* d_ws, size_t ws_size,
                              hipStream_t stream) {
    const float* x     = (const float*)d_in[0];
    const float* W_ih1 = (const float*)d_in[1];
    const float* W_hh1 = (const float*)d_in[2];
    const float* b_ih1 = (const float*)d_in[3];
    const float* b_hh1 = (const float*)d_in[4];
    const float* W_ih2 = (const float*)d_in[5];
    const float* W_hh2 = (const float*)d_in[6];
    const float* b_ih2 = (const float*)d_in[7];
    const float* b_hh2 = (const float*)d_in[8];
    const float* W_fc  = (const float*)d_in[9];
    const float* b_fc  = (const float*)d_in[10];
    float* out = (float*)d_out;
    short* wsS = (short*)d_ws;   // needs 278,528 bytes

    prep_w<<<(PREP_N + 255)/256, 256, 0, stream>>>(W_ih1, W_hh1, W_ih2, W_hh2,
                                                   b_ih1, b_hh1, wsS);
    lstm_mfma<<<B_TOT/8, NTHR, 0, stream>>>(x, wsS, b_ih2, b_hh2, W_fc, b_fc, out);
}